// Round 8
// baseline (538.592 us; speedup 1.0000x reference)
//
#include <hip/hip_runtime.h>
#include <hip/hip_bf16.h>

#define NROWS 32768
#define DDIM  4096
#define ODIM  256
#define EPSV  1e-5f

#define CHUNKS 128
#define RPC    256      // rows per chunk (CHUNKS*RPC == NROWS)

#define BM 128
#define BK 64
#define NKT (DDIM / BK)   // 64 K-steps

typedef __attribute__((ext_vector_type(4))) float          f32x4;
typedef __attribute__((ext_vector_type(8))) __bf16         bf16x8;
typedef __attribute__((ext_vector_type(8))) unsigned short u16x8;
typedef __attribute__((ext_vector_type(4))) unsigned short u16x4;

static __device__ __forceinline__ unsigned short f2bf(float f) {
  return __builtin_bit_cast(unsigned short, __float2bfloat16(f));
}

// ---------------- k1: per-chunk column partial sums (R1-proven) ----------------
__global__ __launch_bounds__(256) void k1_stats(const float* __restrict__ x,
                                                float* __restrict__ psum,
                                                float* __restrict__ psq) {
  const int col = blockIdx.x * 1024 + threadIdx.x * 4;
  const float* p = x + (size_t)blockIdx.y * RPC * DDIM + col;
  f32x4 s = {0.f, 0.f, 0.f, 0.f};
  f32x4 q = {0.f, 0.f, 0.f, 0.f};
#pragma unroll 8
  for (int r = 0; r < RPC; ++r) {
    f32x4 v = *(const f32x4*)p;
    p += DDIM;
    s += v;
    q += v * v;
  }
  *(f32x4*)(psum + (size_t)blockIdx.y * DDIM + col) = s;
  *(f32x4*)(psq  + (size_t)blockIdx.y * DDIM + col) = q;
}

// ---------------- k2a: finalize mean/var -> scale/shift ----------------
__global__ __launch_bounds__(256) void k2_stats_finalize(
    const float* __restrict__ psum, const float* __restrict__ psq,
    const float* __restrict__ gamma, const float* __restrict__ beta,
    float* __restrict__ scale, float* __restrict__ shift) {
  __shared__ float ss[4][64];
  __shared__ float sq[4][64];
  const int lane = threadIdx.x & 63;
  const int g    = threadIdx.x >> 6;          // 0..3
  const int d    = blockIdx.x * 64 + lane;
  float s = 0.f, qq = 0.f;
  for (int c = g * 32; c < (g + 1) * 32; ++c) {
    s  += psum[(size_t)c * DDIM + d];
    qq += psq [(size_t)c * DDIM + d];
  }
  ss[g][lane] = s;
  sq[g][lane] = qq;
  __syncthreads();
  if (g == 0) {
    s  = ss[0][lane] + ss[1][lane] + ss[2][lane] + ss[3][lane];
    qq = sq[0][lane] + sq[1][lane] + sq[2][lane] + sq[3][lane];
    const float inv = 1.0f / (float)NROWS;
    const float mean = s * inv;
    const float var  = fmaxf(qq * inv - mean * mean, 0.f);
    const float a = gamma[d] * rsqrtf(var + EPSV);
    scale[d] = a;
    shift[d] = beta[d] - mean * a;
  }
}

// ---------------- k2b: W fp32 -> bf16 ----------------
__global__ __launch_bounds__(256) void k2_wconv(const float* __restrict__ Wf,
                                                unsigned short* __restrict__ Wb) {
  const size_t i = ((size_t)blockIdx.x * 256 + threadIdx.x) * 4;
  f32x4 v = *(const f32x4*)(Wf + i);
  u16x4 o;
  o[0] = f2bf(v[0]); o[1] = f2bf(v[1]); o[2] = f2bf(v[2]); o[3] = f2bf(v[3]);
  *(u16x4*)(Wb + i) = o;
}

// ---------------- k3: R4-exact schedule, repeated `reps` times for profiling ---
// DIAGNOSTIC: identical output each rep; reps is a runtime arg so the
// compiler cannot collapse the loop. Counters divide by reps.
__global__ __launch_bounds__(512, 1) void k3_bn_gemm(
    const float* __restrict__ x,
    const unsigned short* __restrict__ Wb,
    const float* __restrict__ scale,
    const float* __restrict__ shift,
    const float* __restrict__ bias,
    float* __restrict__ out,
    int reps) {
  __shared__ unsigned short As[2][BM * BK];     // 2 x 16 KB, XOR-swizzled
  __shared__ unsigned short Bs[2][ODIM * BK];   // 2 x 32 KB, XOR-swizzled
  __shared__ float SF[DDIM];                    // 16 KB scale
  __shared__ float SH[DDIM];                    // 16 KB shift

  const int tid = threadIdx.x;
  const int l   = tid & 63;
  const int w   = tid >> 6;     // 0..7
  const int wr  = w >> 2;       // 0..1
  const int wc  = w & 3;        // 0..3
  const size_t bm0 = (size_t)blockIdx.x * BM;

  // --- scale/shift LDS preload ---
  ((f32x4*)SF)[tid * 2]     = ((const f32x4*)scale)[tid * 2];
  ((f32x4*)SF)[tid * 2 + 1] = ((const f32x4*)scale)[tid * 2 + 1];
  ((f32x4*)SH)[tid * 2]     = ((const f32x4*)shift)[tid * 2];
  ((f32x4*)SH)[tid * 2 + 1] = ((const f32x4*)shift)[tid * 2 + 1];

  // --- A staging geometry: thread covers rows rA, rA+64; 8-col unit uA ---
  const int rA = tid >> 3;      // 0..63
  const int uA = tid & 7;       // 0..7
  const int awo = rA * 64 + ((uA ^ (rA & 7)) << 3);   // ushort offset in buf

  // --- fragment LDS offsets (ushort units); kk -> ^32 ---
  int offA[4], offB[4];
#pragma unroll
  for (int i = 0; i < 4; ++i) {
    const int row = wr * 64 + i * 16 + (l & 15);
    offA[i] = row * 64 + (((l >> 4) ^ (row & 7)) << 3);
  }
#pragma unroll
  for (int j = 0; j < 4; ++j) {
    const int row = wc * 64 + j * 16 + (l & 15);
    offB[j] = row * 64 + (((l >> 4) ^ (row & 7)) << 3);
  }

  const int cl = l & 15;
  const int rg = l >> 4;

  for (int rep = 0; rep < reps; ++rep) {
    const float* xp0 = x + (bm0 + rA) * (size_t)DDIM + uA * 8;
    const float* xp1 = xp0 + (size_t)64 * DDIM;
    int ktb = uA * 8;

    const unsigned short* bsrc[4];
#pragma unroll
    for (int q = 0; q < 4; ++q) {
      const int p  = w * 256 + q * 64 + l;
      const int o  = p >> 3;
      const int up = p & 7;
      bsrc[q] = Wb + (size_t)o * DDIM + ((up ^ (o & 7)) << 3);
    }

    const f32x4 zero = {0.f, 0.f, 0.f, 0.f};
    f32x4 acc[4][4];
#pragma unroll
    for (int i = 0; i < 4; ++i)
#pragma unroll
      for (int j = 0; j < 4; ++j) acc[i][j] = zero;

#define ISSUE_A(V00, V01, V10, V11)                                            \
  asm volatile("global_load_dwordx4 %0, %1, off" : "=v"(V00) : "v"(xp0));      \
  asm volatile("global_load_dwordx4 %0, %1, off" : "=v"(V01) : "v"(xp0 + 4));  \
  asm volatile("global_load_dwordx4 %0, %1, off" : "=v"(V10) : "v"(xp1));      \
  asm volatile("global_load_dwordx4 %0, %1, off" : "=v"(V11) : "v"(xp1 + 4));  \
  asm volatile("" ::: "memory");

#define ISSUE_B(BUFI)                                                          \
  _Pragma("unroll")                                                            \
  for (int q = 0; q < 4; ++q) {                                                \
    __builtin_amdgcn_global_load_lds(                                          \
        (__attribute__((address_space(1))) void*)bsrc[q],                      \
        (__attribute__((address_space(3))) void*)(                             \
            &Bs[BUFI][(w * 256 + q * 64) * 8]),                                \
        16, 0, 0);                                                             \
    bsrc[q] += BK;                                                             \
  }

#define TRANSFORM_WRITE(BUFI, V00, V01, V10, V11)                              \
  {                                                                            \
    f32x4 sa0 = *(const f32x4*)&SF[ktb];                                       \
    f32x4 sa1 = *(const f32x4*)&SF[ktb + 4];                                   \
    f32x4 sc0 = *(const f32x4*)&SH[ktb];                                       \
    f32x4 sc1 = *(const f32x4*)&SH[ktb + 4];                                   \
    ktb += BK;                                                                 \
    u16x8 pk0, pk1;                                                            \
    _Pragma("unroll")                                                          \
    for (int e = 0; e < 4; ++e) {                                              \
      pk0[e]     = f2bf(fmaxf(V00[e] * sa0[e] + sc0[e], 0.f));                 \
      pk0[e + 4] = f2bf(fmaxf(V01[e] * sa1[e] + sc1[e], 0.f));                 \
      pk1[e]     = f2bf(fmaxf(V10[e] * sa0[e] + sc0[e], 0.f));                 \
      pk1[e + 4] = f2bf(fmaxf(V11[e] * sa1[e] + sc1[e], 0.f));                 \
    }                                                                          \
    *(u16x8*)&As[BUFI][awo]        = pk0;                                      \
    *(u16x8*)&As[BUFI][awo + 4096] = pk1;                                      \
  }

#define MFMA_PHASE(BUFI)                                                       \
  _Pragma("unroll")                                                            \
  for (int kk = 0; kk < 2; ++kk) {                                             \
    const int kx = kk << 5;                                                    \
    bf16x8 af[4], bfr[4];                                                      \
    _Pragma("unroll")                                                          \
    for (int i = 0; i < 4; ++i)                                                \
      af[i] = __builtin_bit_cast(bf16x8,                                       \
                                 *(const u16x8*)&As[BUFI][offA[i] ^ kx]);      \
    _Pragma("unroll")                                                          \
    for (int j = 0; j < 4; ++j)                                                \
      bfr[j] = __builtin_bit_cast(bf16x8,                                      \
                                  *(const u16x8*)&Bs[BUFI][offB[j] ^ kx]);     \
    _Pragma("unroll")                                                          \
    for (int i = 0; i < 4; ++i)                                                \
      _Pragma("unroll")                                                        \
      for (int j = 0; j < 4; ++j)                                              \
        acc[i][j] = __builtin_amdgcn_mfma_f32_16x16x32_bf16(                   \
            af[i], bfr[j], acc[i][j], 0, 0, 0);                                \
  }

    // ---- prologue: stage tile 0 into buffers [0] ----
    {
      f32x4 v00, v01, v10, v11;
      ISSUE_A(v00, v01, v10, v11);
      ISSUE_B(0);
      xp0 += BK; xp1 += BK;
      asm volatile("s_waitcnt lgkmcnt(0)" ::: "memory");
      __builtin_amdgcn_sched_barrier(0);
      __builtin_amdgcn_s_barrier();
      asm volatile("s_waitcnt vmcnt(4)" ::: "memory");   // A0 done, B0 flying
      __builtin_amdgcn_sched_barrier(0);
      TRANSFORM_WRITE(0, v00, v01, v10, v11);
      asm volatile("s_waitcnt vmcnt(0) lgkmcnt(0)" ::: "memory");
      __builtin_amdgcn_sched_barrier(0);
      __builtin_amdgcn_s_barrier();
    }

#define STEP(CUR, PF)                                                          \
  do {                                                                         \
    f32x4 v00, v01, v10, v11;                                                  \
    if (PF) {                                                                  \
      ISSUE_A(v00, v01, v10, v11);                                             \
      ISSUE_B((CUR) ^ 1);                                                      \
      xp0 += BK; xp1 += BK;                                                    \
    }                                                                          \
    MFMA_PHASE(CUR);                                                           \
    if (PF) {                                                                  \
      asm volatile("s_waitcnt vmcnt(4)" ::: "memory");                         \
      __builtin_amdgcn_sched_barrier(0);                                       \
      TRANSFORM_WRITE((CUR) ^ 1, v00, v01, v10, v11);                          \
    }                                                                          \
    asm volatile("s_waitcnt vmcnt(0) lgkmcnt(0)" ::: "memory");                \
    __builtin_amdgcn_sched_barrier(0);                                         \
    __builtin_amdgcn_s_barrier();                                              \
  } while (0)

    for (int kt = 0; kt < NKT - 2; kt += 2) {
      STEP(0, true);
      STEP(1, true);
    }
    STEP(0, true);    // step 62, prefetch tile 63 into buf 1
    STEP(1, false);   // step 63
#undef STEP
#undef MFMA_PHASE
#undef TRANSFORM_WRITE
#undef ISSUE_B
#undef ISSUE_A

    // epilogue: C/D layout col=l&15, row=(l>>4)*4+rr
#pragma unroll
    for (int j = 0; j < 4; ++j) {
      const int oc = wc * 64 + j * 16 + cl;
      const float bv = bias[oc];
#pragma unroll
      for (int i = 0; i < 4; ++i) {
        const size_t r0 = bm0 + wr * 64 + i * 16 + rg * 4;
#pragma unroll
        for (int rr = 0; rr < 4; ++rr) {
          out[(r0 + rr) * ODIM + oc] = acc[i][j][rr] + bv;
        }
      }
    }
    __syncthreads();   // all stores/reads done before next rep restages
  }
}

extern "C" void kernel_launch(void* const* d_in, const int* in_sizes, int n_in,
                              void* d_out, int out_size, void* d_ws, size_t ws_size,
                              hipStream_t stream) {
  const float* x     = (const float*)d_in[0];
  const float* gamma = (const float*)d_in[1];
  const float* beta  = (const float*)d_in[2];
  const float* W     = (const float*)d_in[3];
  const float* b     = (const float*)d_in[4];
  float* out = (float*)d_out;

  float* psum  = (float*)d_ws;
  float* psq   = psum + (size_t)CHUNKS * DDIM;
  float* scale = psum + 2 * (size_t)CHUNKS * DDIM;
  float* shift = scale + DDIM;
  unsigned short* Wb = (unsigned short*)(shift + DDIM);

  k1_stats<<<dim3(4, CHUNKS), 256, 0, stream>>>(x, psum, psq);
  k2_stats_finalize<<<DDIM / 64, 256, 0, stream>>>(psum, psq, gamma, beta, scale, shift);
  k2_wconv<<<(ODIM * DDIM) / 1024, 256, 0, stream>>>(W, Wb);
  k3_bn_gemm<<<NROWS / BM, 512, 0, stream>>>(x, Wb, scale, shift, b, out, 3);
}

// Round 9
// 301.327 us; speedup vs baseline: 1.7874x; 1.7874x over previous
//
#include <hip/hip_runtime.h>
#include <hip/hip_bf16.h>

#define NROWS 32768
#define DDIM  4096
#define ODIM  256
#define EPSV  1e-5f

#define CHUNKS 128
#define RPC    256      // rows per chunk (CHUNKS*RPC == NROWS)

#define BM 128
#define BN 128          // N split in two halves -> 512 blocks = 2/CU
#define BK 64
#define NKT (DDIM / BK)   // 64 K-steps

typedef __attribute__((ext_vector_type(4))) float          f32x4;
typedef __attribute__((ext_vector_type(8))) __bf16         bf16x8;
typedef __attribute__((ext_vector_type(8))) unsigned short u16x8;
typedef __attribute__((ext_vector_type(4))) unsigned short u16x4;

static __device__ __forceinline__ unsigned short f2bf(float f) {
  return __builtin_bit_cast(unsigned short, __float2bfloat16(f));
}
static __device__ __forceinline__ float bf2f(unsigned short u) {
  return __builtin_bit_cast(float, ((unsigned)u) << 16);
}

// ---------------- k1: per-chunk column partial sums (R1-proven, ~86us) --------
__global__ __launch_bounds__(256) void k1_stats(const float* __restrict__ x,
                                                float* __restrict__ psum,
                                                float* __restrict__ psq) {
  const int col = blockIdx.x * 1024 + threadIdx.x * 4;
  const float* p = x + (size_t)blockIdx.y * RPC * DDIM + col;
  f32x4 s = {0.f, 0.f, 0.f, 0.f};
  f32x4 q = {0.f, 0.f, 0.f, 0.f};
#pragma unroll 8
  for (int r = 0; r < RPC; ++r) {
    f32x4 v = *(const f32x4*)p;
    p += DDIM;
    s += v;
    q += v * v;
  }
  *(f32x4*)(psum + (size_t)blockIdx.y * DDIM + col) = s;
  *(f32x4*)(psq  + (size_t)blockIdx.y * DDIM + col) = q;
}

// ------- k2: finalize mean/var -> bf16 scale/shift  +  W fp32->bf16 (merged) ---
__global__ __launch_bounds__(256) void k2_finalize_wconv(
    const float* __restrict__ psum, const float* __restrict__ psq,
    const float* __restrict__ gamma, const float* __restrict__ beta,
    const float* __restrict__ Wf,
    unsigned short* __restrict__ ssb, unsigned short* __restrict__ shb,
    unsigned short* __restrict__ Wb) {
  if (blockIdx.x < 64) {
    __shared__ float ss[4][64];
    __shared__ float sq[4][64];
    const int lane = threadIdx.x & 63;
    const int g    = threadIdx.x >> 6;          // 0..3
    const int d    = blockIdx.x * 64 + lane;
    float s = 0.f, qq = 0.f;
    for (int c = g * 32; c < (g + 1) * 32; ++c) {
      s  += psum[(size_t)c * DDIM + d];
      qq += psq [(size_t)c * DDIM + d];
    }
    ss[g][lane] = s;
    sq[g][lane] = qq;
    __syncthreads();
    if (g == 0) {
      s  = ss[0][lane] + ss[1][lane] + ss[2][lane] + ss[3][lane];
      qq = sq[0][lane] + sq[1][lane] + sq[2][lane] + sq[3][lane];
      const float inv = 1.0f / (float)NROWS;
      const float mean = s * inv;
      const float var  = fmaxf(qq * inv - mean * mean, 0.f);
      const float a = gamma[d] * rsqrtf(var + EPSV);
      ssb[d] = f2bf(a);
      shb[d] = f2bf(beta[d] - mean * a);
    }
  } else {
    const size_t i = ((size_t)(blockIdx.x - 64) * 256 + threadIdx.x) * 4;
    f32x4 v = *(const f32x4*)(Wf + i);
    u16x4 o;
    o[0] = f2bf(v[0]); o[1] = f2bf(v[1]); o[2] = f2bf(v[2]); o[3] = f2bf(v[3]);
    *(u16x4*)(Wb + i) = o;
  }
}

// ---------------- k3: fused normalize+relu+bf16 GEMM, 2 blocks/CU --------------
// 128x128 tile (N halved), 256 thr (4 waves, 2x2 of 64x64). 512 blocks ->
// 2 blocks/CU: cross-block overlap fills the barrier/latency gaps (m114).
// R4-proven asm-pinned counted-vmcnt schedule, dbuf As/Bs, 80 KB LDS.
__global__ __launch_bounds__(256, 2) void k3_bn_gemm(
    const float* __restrict__ x,
    const unsigned short* __restrict__ Wb,
    const unsigned short* __restrict__ ssg,
    const unsigned short* __restrict__ shg,
    const float* __restrict__ bias,
    float* __restrict__ out) {
  __shared__ unsigned short As[2][BM * BK];     // 2 x 16 KB, XOR-swizzled
  __shared__ unsigned short Bs[2][BN * BK];     // 2 x 16 KB, XOR-swizzled
  __shared__ unsigned short SFb[DDIM];          // 8 KB scale (bf16)
  __shared__ unsigned short SHb[DDIM];          // 8 KB shift (bf16)

  const int tid = threadIdx.x;
  const int l   = tid & 63;
  const int w   = tid >> 6;     // 0..3
  const int wr  = w >> 1;       // 0..1
  const int wc  = w & 1;        // 0..1
  // block swizzle: pair (m, nh=0/1) adjacent on the same (assumed) XCD,
  // M-contiguous within an XCD for x L2/L3 locality.
  const int b   = blockIdx.x;           // 0..511
  const int xcd = b & 7;
  const int j8  = b >> 3;               // 0..63
  const int m   = xcd * 32 + (j8 >> 1); // 0..255
  const int nh  = j8 & 1;               // N half
  const size_t bm0 = (size_t)m * BM;
  const int ncol0  = nh * BN;

  // --- scale/shift preload -> bf16 LDS (each thread 16 cols) ---
  {
    const int c0 = tid * 16;
    *(u16x8*)&SFb[c0]     = *(const u16x8*)(ssg + c0);
    *(u16x8*)&SFb[c0 + 8] = *(const u16x8*)(ssg + c0 + 8);
    *(u16x8*)&SHb[c0]     = *(const u16x8*)(shg + c0);
    *(u16x8*)&SHb[c0 + 8] = *(const u16x8*)(shg + c0 + 8);
  }

  // --- A staging geometry: thread covers row rA (0..127), half h (32 cols) ---
  const int rA = tid >> 1;      // 0..127
  const int h  = tid & 1;       // 0..1
  const float* xq = x + (bm0 + rA) * (size_t)DDIM + h * 32;
  const int sw = rA & 7;
  int ktb = h * 32;             // scale/shift col base (ushort units)

  // --- B staging: gl_lds, linear LDS dest + inverse-swizzled global src ---
  const unsigned short* bsrc[4];
#pragma unroll
  for (int q = 0; q < 4; ++q) {
    const int p  = q * 256 + tid;   // 16B-unit index into a B buffer (0..1023)
    const int o  = p >> 3;          // local W row 0..127
    const int up = p & 7;
    bsrc[q] = Wb + (size_t)(ncol0 + o) * DDIM + ((up ^ (o & 7)) << 3);
  }

  // --- fragment LDS offsets (ushort units); kk -> ^32 ---
  int offA[4], offB[4];
#pragma unroll
  for (int i = 0; i < 4; ++i) {
    const int row = wr * 64 + i * 16 + (l & 15);
    offA[i] = row * 64 + (((l >> 4) ^ (row & 7)) << 3);
  }
#pragma unroll
  for (int jj = 0; jj < 4; ++jj) {
    const int row = wc * 64 + jj * 16 + (l & 15);
    offB[jj] = row * 64 + (((l >> 4) ^ (row & 7)) << 3);
  }

  const f32x4 zero = {0.f, 0.f, 0.f, 0.f};
  f32x4 acc[4][4];
#pragma unroll
  for (int i = 0; i < 4; ++i)
#pragma unroll
    for (int jj = 0; jj < 4; ++jj) acc[i][jj] = zero;

#define ISSUE_A(S)                                                             \
  asm volatile("global_load_dwordx4 %0, %1, off"            : "=v"(S[0]) : "v"(xq)); \
  asm volatile("global_load_dwordx4 %0, %1, off offset:16"  : "=v"(S[1]) : "v"(xq)); \
  asm volatile("global_load_dwordx4 %0, %1, off offset:32"  : "=v"(S[2]) : "v"(xq)); \
  asm volatile("global_load_dwordx4 %0, %1, off offset:48"  : "=v"(S[3]) : "v"(xq)); \
  asm volatile("global_load_dwordx4 %0, %1, off offset:64"  : "=v"(S[4]) : "v"(xq)); \
  asm volatile("global_load_dwordx4 %0, %1, off offset:80"  : "=v"(S[5]) : "v"(xq)); \
  asm volatile("global_load_dwordx4 %0, %1, off offset:96"  : "=v"(S[6]) : "v"(xq)); \
  asm volatile("global_load_dwordx4 %0, %1, off offset:112" : "=v"(S[7]) : "v"(xq)); \
  xq += BK;                                                                    \
  asm volatile("" ::: "memory");

#define ISSUE_B(BUFI)                                                          \
  _Pragma("unroll")                                                            \
  for (int q = 0; q < 4; ++q) {                                                \
    __builtin_amdgcn_global_load_lds(                                          \
        (__attribute__((address_space(1))) void*)bsrc[q],                      \
        (__attribute__((address_space(3))) void*)(                             \
            &Bs[BUFI][(q * 256 + (tid & ~63)) * 8]),                           \
        16, 0, 0);                                                             \
    bsrc[q] += BK;                                                             \
  }                                                                            \
  asm volatile("" ::: "memory");

#define TRANSFORM_WRITE(BUFI, S)                                               \
  {                                                                            \
    _Pragma("unroll")                                                          \
    for (int u = 0; u < 4; ++u) {                                              \
      u16x8 av = *(const u16x8*)&SFb[ktb + u * 8];                             \
      u16x8 cv = *(const u16x8*)&SHb[ktb + u * 8];                             \
      u16x8 pk;                                                                \
      _Pragma("unroll")                                                        \
      for (int e = 0; e < 4; ++e) {                                            \
        pk[e]     = f2bf(fmaxf(S[2 * u][e]     * bf2f(av[e])     + bf2f(cv[e]),     0.f)); \
        pk[e + 4] = f2bf(fmaxf(S[2 * u + 1][e] * bf2f(av[e + 4]) + bf2f(cv[e + 4]), 0.f)); \
      }                                                                        \
      *(u16x8*)&As[BUFI][rA * 64 + (((h * 4 + u) ^ sw) << 3)] = pk;            \
    }                                                                          \
    ktb += BK;                                                                 \
  }

#define MFMA_PHASE(BUFI)                                                       \
  __builtin_amdgcn_s_setprio(1);                                              \
  _Pragma("unroll")                                                            \
  for (int kk = 0; kk < 2; ++kk) {                                             \
    const int kx = kk << 5;                                                    \
    bf16x8 af[4], bfr[4];                                                      \
    _Pragma("unroll")                                                          \
    for (int i = 0; i < 4; ++i)                                                \
      af[i] = __builtin_bit_cast(bf16x8,                                       \
                                 *(const u16x8*)&As[BUFI][offA[i] ^ kx]);      \
    _Pragma("unroll")                                                          \
    for (int jj = 0; jj < 4; ++jj)                                             \
      bfr[jj] = __builtin_bit_cast(bf16x8,                                     \
                                   *(const u16x8*)&Bs[BUFI][offB[jj] ^ kx]);   \
    _Pragma("unroll")                                                          \
    for (int i = 0; i < 4; ++i)                                                \
      _Pragma("unroll")                                                        \
      for (int jj = 0; jj < 4; ++jj)                                           \
        acc[i][jj] = __builtin_amdgcn_mfma_f32_16x16x32_bf16(                  \
            af[i], bfr[jj], acc[i][jj], 0, 0, 0);                              \
  }                                                                            \
  __builtin_amdgcn_s_setprio(0);

  // ---- prologue: stage tile 0 into buffers [0] ----
  {
    f32x4 S[8];
    ISSUE_A(S);
    ISSUE_B(0);
    asm volatile("s_waitcnt lgkmcnt(0)" ::: "memory");   // SFb/SHb stores done
    __builtin_amdgcn_sched_barrier(0);
    __builtin_amdgcn_s_barrier();                        // SFb/SHb visible
    asm volatile("s_waitcnt vmcnt(4)" ::: "memory");     // A0 landed, B0 flying
    __builtin_amdgcn_sched_barrier(0);
    TRANSFORM_WRITE(0, S);
    asm volatile("s_waitcnt vmcnt(0) lgkmcnt(0)" ::: "memory");
    __builtin_amdgcn_sched_barrier(0);
    __builtin_amdgcn_s_barrier();
  }

#define STEP(CUR, PF)                                                          \
  do {                                                                         \
    f32x4 S[8];                                                                \
    if (PF) {                                                                  \
      ISSUE_A(S);                                                              \
      ISSUE_B((CUR) ^ 1);                                                      \
    }                                                                          \
    MFMA_PHASE(CUR);                                                           \
    if (PF) {                                                                  \
      asm volatile("s_waitcnt vmcnt(4)" ::: "memory");                         \
      __builtin_amdgcn_sched_barrier(0);                                       \
      TRANSFORM_WRITE((CUR) ^ 1, S);                                           \
    }                                                                          \
    asm volatile("s_waitcnt vmcnt(0) lgkmcnt(0)" ::: "memory");                \
    __builtin_amdgcn_sched_barrier(0);                                         \
    __builtin_amdgcn_s_barrier();                                              \
  } while (0)

  for (int kt = 0; kt < NKT - 2; kt += 2) {
    STEP(0, true);
    STEP(1, true);
  }
  STEP(0, true);    // step 62, prefetch tile 63 into buf 1
  STEP(1, false);   // step 63
#undef STEP
#undef MFMA_PHASE
#undef TRANSFORM_WRITE
#undef ISSUE_B
#undef ISSUE_A

  // epilogue: C/D layout col=l&15, row=(l>>4)*4+rr
  const int cl = l & 15;
  const int rg = l >> 4;
#pragma unroll
  for (int jj = 0; jj < 4; ++jj) {
    const int oc = ncol0 + wc * 64 + jj * 16 + cl;
    const float bv = bias[oc];
#pragma unroll
    for (int i = 0; i < 4; ++i) {
      const size_t r0 = bm0 + wr * 64 + i * 16 + rg * 4;
#pragma unroll
      for (int rr = 0; rr < 4; ++rr) {
        out[(r0 + rr) * ODIM + oc] = acc[i][jj][rr] + bv;
      }
    }
  }
}

extern "C" void kernel_launch(void* const* d_in, const int* in_sizes, int n_in,
                              void* d_out, int out_size, void* d_ws, size_t ws_size,
                              hipStream_t stream) {
  const float* x     = (const float*)d_in[0];
  const float* gamma = (const float*)d_in[1];
  const float* beta  = (const float*)d_in[2];
  const float* W     = (const float*)d_in[3];
  const float* b     = (const float*)d_in[4];
  float* out = (float*)d_out;

  // ws: psum[128][4096] | psq[128][4096] | Wb bf16 | ssb bf16 | shb bf16
  float* psum  = (float*)d_ws;
  float* psq   = psum + (size_t)CHUNKS * DDIM;
  unsigned short* Wb  = (unsigned short*)(psq + (size_t)CHUNKS * DDIM);
  unsigned short* ssb = Wb + (size_t)ODIM * DDIM;
  unsigned short* shb = ssb + DDIM;

  k1_stats<<<dim3(4, CHUNKS), 256, 0, stream>>>(x, psum, psq);
  k2_finalize_wconv<<<64 + (ODIM * DDIM) / 1024, 256, 0, stream>>>(
      psum, psq, gamma, beta, W, ssb, shb, Wb);
  k3_bn_gemm<<<(NROWS / BM) * 2, 256, 0, stream>>>(x, Wb, ssb, shb, b, out);
}

// Round 10
// 248.018 us; speedup vs baseline: 2.1716x; 1.2149x over previous
//
#include <hip/hip_runtime.h>
#include <hip/hip_bf16.h>

#define NROWS 32768
#define DDIM  4096
#define ODIM  256
#define EPSV  1e-5f

#define CHUNKS 128
#define RPC    256      // rows per chunk (CHUNKS*RPC == NROWS)

#define BM 128
#define BK 64
#define NKT (DDIM / BK)   // 64 K-steps

typedef __attribute__((ext_vector_type(4))) float          f32x4;
typedef __attribute__((ext_vector_type(8))) __bf16         bf16x8;
typedef __attribute__((ext_vector_type(8))) unsigned short u16x8;
typedef __attribute__((ext_vector_type(4))) unsigned short u16x4;

static __device__ __forceinline__ unsigned short f2bf(float f) {
  return __builtin_bit_cast(unsigned short, __float2bfloat16(f));
}

// ---------------- k1: per-chunk column partial sums (R1-proven) ----------------
__global__ __launch_bounds__(256) void k1_stats(const float* __restrict__ x,
                                                float* __restrict__ psum,
                                                float* __restrict__ psq) {
  const int col = blockIdx.x * 1024 + threadIdx.x * 4;
  const float* p = x + (size_t)blockIdx.y * RPC * DDIM + col;
  f32x4 s = {0.f, 0.f, 0.f, 0.f};
  f32x4 q = {0.f, 0.f, 0.f, 0.f};
#pragma unroll 8
  for (int r = 0; r < RPC; ++r) {
    f32x4 v = *(const f32x4*)p;
    p += DDIM;
    s += v;
    q += v * v;
  }
  *(f32x4*)(psum + (size_t)blockIdx.y * DDIM + col) = s;
  *(f32x4*)(psq  + (size_t)blockIdx.y * DDIM + col) = q;
}

// ---------------- k2a: finalize mean/var -> scale/shift (fp32) ----------------
__global__ __launch_bounds__(256) void k2_stats_finalize(
    const float* __restrict__ psum, const float* __restrict__ psq,
    const float* __restrict__ gamma, const float* __restrict__ beta,
    float* __restrict__ scale, float* __restrict__ shift) {
  __shared__ float ss[4][64];
  __shared__ float sq[4][64];
  const int lane = threadIdx.x & 63;
  const int g    = threadIdx.x >> 6;          // 0..3
  const int d    = blockIdx.x * 64 + lane;
  float s = 0.f, qq = 0.f;
  for (int c = g * 32; c < (g + 1) * 32; ++c) {
    s  += psum[(size_t)c * DDIM + d];
    qq += psq [(size_t)c * DDIM + d];
  }
  ss[g][lane] = s;
  sq[g][lane] = qq;
  __syncthreads();
  if (g == 0) {
    s  = ss[0][lane] + ss[1][lane] + ss[2][lane] + ss[3][lane];
    qq = sq[0][lane] + sq[1][lane] + sq[2][lane] + sq[3][lane];
    const float inv = 1.0f / (float)NROWS;
    const float mean = s * inv;
    const float var  = fmaxf(qq * inv - mean * mean, 0.f);
    const float a = gamma[d] * rsqrtf(var + EPSV);
    scale[d] = a;
    shift[d] = beta[d] - mean * a;
  }
}

// ---------------- k2b: W fp32 -> bf16 ----------------
__global__ __launch_bounds__(256) void k2_wconv(const float* __restrict__ Wf,
                                                unsigned short* __restrict__ Wb) {
  const size_t i = ((size_t)blockIdx.x * 256 + threadIdx.x) * 4;
  f32x4 v = *(const f32x4*)(Wf + i);
  u16x4 o;
  o[0] = f2bf(v[0]); o[1] = f2bf(v[1]); o[2] = f2bf(v[2]); o[3] = f2bf(v[3]);
  *(u16x4*)(Wb + i) = o;
}

// ---------------- k3: streaming-A fused normalize+relu+bf16 GEMM ---------------
// 8 waves, wave = 16 rows x 256 cols (acc[16]). A: global->reg->transform->
// MFMA operand DIRECTLY (the per-lane load IS the A-fragment: row=l&15,
// cols (l>>4)*8). A 2-deep in regs (~1.5 steps in flight). B: W via
// double-buffered LDS (gl_lds). Counted waits vmcnt(8)/vmcnt(4), one
// s_barrier/step (B flip only).
__global__ __launch_bounds__(512, 1) void k3_bn_gemm(
    const float* __restrict__ x,
    const unsigned short* __restrict__ Wb,
    const float* __restrict__ scale,
    const float* __restrict__ shift,
    const float* __restrict__ bias,
    float* __restrict__ out) {
  __shared__ unsigned short Bs[2][ODIM * BK];   // 2 x 32 KB
  __shared__ float SF[DDIM];                    // 16 KB
  __shared__ float SH[DDIM];                    // 16 KB

  const int tid = threadIdx.x;
  const int l   = tid & 63;
  const int w   = tid >> 6;     // 0..7 = M-wave
  const int lr  = l & 15;       // frag row
  const int lc  = l >> 4;       // frag col-group (0..3)
  const size_t bm0 = (size_t)blockIdx.x * BM;

  // --- SF/SH preload (8 f32 each per thread) ---
  {
    const int c0 = tid * 8;
    *(f32x4*)&SF[c0]     = *(const f32x4*)(scale + c0);
    *(f32x4*)&SF[c0 + 4] = *(const f32x4*)(scale + c0 + 4);
    *(f32x4*)&SH[c0]     = *(const f32x4*)(shift + c0);
    *(f32x4*)&SH[c0 + 4] = *(const f32x4*)(shift + c0 + 4);
  }

  // --- A stream pointer: lane covers row (bm0+w*16+lr), cols lc*8.. ---
  const float* xrp = x + (bm0 + w * 16 + lr) * (size_t)DDIM + lc * 8;
  int ktb = 0;                  // transform col base (advances 64/step)

  // --- B staging: gl_lds, linear dest + inverse-swizzled global src ---
  const unsigned short* bsrc[4];
#pragma unroll
  for (int q = 0; q < 4; ++q) {
    const int p  = w * 256 + q * 64 + l;   // 16B-unit index
    const int o  = p >> 3;                 // W row 0..255
    const int up = p & 7;
    bsrc[q] = Wb + (size_t)o * DDIM + ((up ^ (o & 7)) << 3);
  }

  // --- B frag base: row=lr, col-unit lc ^ (lr&7); +j*1024 for j frags ---
  const int offB0 = lr * 64 + ((lc ^ (l & 7)) << 3);

  const f32x4 zero = {0.f, 0.f, 0.f, 0.f};
  f32x4 acc[16];
#pragma unroll
  for (int j = 0; j < 16; ++j) acc[j] = zero;

  f32x4 Ar0[4], Ar1[4];         // raw A double-buffer (16 f32 each)
  u16x8 pk0a, pk0b, pk1a, pk1b; // packed A frags (kk=0,1) x 2 steps

  // lane loads: bytes 0,16 (kk=0) and 128,144 (kk=1) from xrp
#define ISSUE_A(S)                                                             \
  asm volatile("global_load_dwordx4 %0, %1, off"            : "=v"(S[0]) : "v"(xrp)); \
  asm volatile("global_load_dwordx4 %0, %1, off offset:16"  : "=v"(S[1]) : "v"(xrp)); \
  asm volatile("global_load_dwordx4 %0, %1, off offset:128" : "=v"(S[2]) : "v"(xrp)); \
  asm volatile("global_load_dwordx4 %0, %1, off offset:144" : "=v"(S[3]) : "v"(xrp)); \
  xrp += BK;                                                                   \
  asm volatile("" ::: "memory");

#define ISSUE_B(BUFI)                                                          \
  _Pragma("unroll")                                                            \
  for (int q = 0; q < 4; ++q) {                                                \
    __builtin_amdgcn_global_load_lds(                                          \
        (__attribute__((address_space(1))) void*)bsrc[q],                      \
        (__attribute__((address_space(3))) void*)(                             \
            &Bs[BUFI][(w * 256 + q * 64) * 8]),                                \
        16, 0, 0);                                                             \
    bsrc[q] += BK;                                                             \
  }                                                                            \
  asm volatile("" ::: "memory");

#define TRANSFORM(S, PKA, PKB)                                                 \
  {                                                                            \
    const int tc = ktb + lc * 8;                                               \
    f32x4 sa0 = *(const f32x4*)&SF[tc];                                        \
    f32x4 sa1 = *(const f32x4*)&SF[tc + 4];                                    \
    f32x4 ha0 = *(const f32x4*)&SH[tc];                                        \
    f32x4 ha1 = *(const f32x4*)&SH[tc + 4];                                    \
    f32x4 sb0 = *(const f32x4*)&SF[tc + 32];                                   \
    f32x4 sb1 = *(const f32x4*)&SF[tc + 36];                                   \
    f32x4 hb0 = *(const f32x4*)&SH[tc + 32];                                   \
    f32x4 hb1 = *(const f32x4*)&SH[tc + 36];                                   \
    ktb += BK;                                                                 \
    _Pragma("unroll")                                                          \
    for (int e = 0; e < 4; ++e) {                                              \
      PKA[e]     = f2bf(fmaxf(S[0][e] * sa0[e] + ha0[e], 0.f));                \
      PKA[e + 4] = f2bf(fmaxf(S[1][e] * sa1[e] + ha1[e], 0.f));                \
      PKB[e]     = f2bf(fmaxf(S[2][e] * sb0[e] + hb0[e], 0.f));                \
      PKB[e + 4] = f2bf(fmaxf(S[3][e] * sb1[e] + hb1[e], 0.f));                \
    }                                                                          \
  }

#define MFMA_PHASE(CUR, PKA, PKB)                                              \
  _Pragma("unroll")                                                            \
  for (int kk = 0; kk < 2; ++kk) {                                             \
    const bf16x8 af = __builtin_bit_cast(bf16x8, kk ? PKB : PKA);              \
    const int kbase = (offB0 ^ (kk << 5));                                     \
    _Pragma("unroll")                                                          \
    for (int j = 0; j < 16; ++j) {                                             \
      bf16x8 bf = __builtin_bit_cast(                                          \
          bf16x8, *(const u16x8*)&Bs[CUR][kbase + j * 1024]);                  \
      acc[j] = __builtin_amdgcn_mfma_f32_16x16x32_bf16(af, bf, acc[j], 0, 0, 0); \
    }                                                                          \
  }

  // ---- prologue: B(0)->Bs[0], A(0)->Ar0, A(1)->Ar1 ----
  {
    ISSUE_B(0);
    ISSUE_A(Ar0);
    ISSUE_A(Ar1);
    asm volatile("s_waitcnt lgkmcnt(0)" ::: "memory");  // SF/SH stores done
    __builtin_amdgcn_sched_barrier(0);
    __builtin_amdgcn_s_barrier();                       // SF/SH visible
    asm volatile("s_waitcnt vmcnt(4)" ::: "memory");    // B0+A0 done, A1 flying
    __builtin_amdgcn_sched_barrier(0);
    TRANSFORM(Ar0, pk0a, pk0b);                         // cols 0..63
    __builtin_amdgcn_s_barrier();                       // B0 staged by all
  }

  // step t: read Bs[t&1] with pk(t); stage B(t+1); issue A(t+2)->Ar[t&1];
  // transform A(t+1)=Ar[(t+1)&1] -> pk(t+1).
#define STEP(CUR, ARF, ART, PKCA, PKCB, PKNA, PKNB)                            \
  do {                                                                         \
    ISSUE_B((CUR) ^ 1);                                                        \
    ISSUE_A(ARF);                                                              \
    MFMA_PHASE(CUR, PKCA, PKCB);                                               \
    asm volatile("s_waitcnt vmcnt(8)" ::: "memory");   /* A(t+1) home */       \
    __builtin_amdgcn_sched_barrier(0);                                         \
    TRANSFORM(ART, PKNA, PKNB);                                                \
    asm volatile("s_waitcnt vmcnt(4)" ::: "memory");   /* B(t+1) in LDS */     \
    __builtin_amdgcn_sched_barrier(0);                                         \
    __builtin_amdgcn_s_barrier();                                              \
  } while (0)

  // steps 0..61 (31 unrolled pairs)
  for (int kt = 0; kt < NKT - 2; kt += 2) {
    STEP(0, Ar0, Ar1, pk0a, pk0b, pk1a, pk1b);
    STEP(1, Ar1, Ar0, pk1a, pk1b, pk0a, pk0b);
  }
  // step 62 (CUR=0): stage B(63); A(63) already in Ar1; no new A
  {
    ISSUE_B(1);
    MFMA_PHASE(0, pk0a, pk0b);
    asm volatile("s_waitcnt vmcnt(4)" ::: "memory");   // A(63) home
    __builtin_amdgcn_sched_barrier(0);
    TRANSFORM(Ar1, pk1a, pk1b);
    asm volatile("s_waitcnt vmcnt(0) lgkmcnt(0)" ::: "memory");
    __builtin_amdgcn_sched_barrier(0);
    __builtin_amdgcn_s_barrier();
  }
  // step 63
  MFMA_PHASE(1, pk1a, pk1b);

#undef STEP
#undef MFMA_PHASE
#undef TRANSFORM
#undef ISSUE_B
#undef ISSUE_A

  // epilogue: C/D layout col=l&15(=lr), row=(l>>4)*4+rr(=lc*4+rr)
#pragma unroll
  for (int j = 0; j < 16; ++j) {
    const int oc = j * 16 + lr;
    const float bv = bias[oc];
    const size_t r0 = bm0 + w * 16 + lc * 4;
#pragma unroll
    for (int rr = 0; rr < 4; ++rr) {
      out[(r0 + rr) * ODIM + oc] = acc[j][rr] + bv;
    }
  }
}

extern "C" void kernel_launch(void* const* d_in, const int* in_sizes, int n_in,
                              void* d_out, int out_size, void* d_ws, size_t ws_size,
                              hipStream_t stream) {
  const float* x     = (const float*)d_in[0];
  const float* gamma = (const float*)d_in[1];
  const float* beta  = (const float*)d_in[2];
  const float* W     = (const float*)d_in[3];
  const float* b     = (const float*)d_in[4];
  float* out = (float*)d_out;

  float* psum  = (float*)d_ws;
  float* psq   = psum + (size_t)CHUNKS * DDIM;
  float* scale = psum + 2 * (size_t)CHUNKS * DDIM;
  float* shift = scale + DDIM;
  unsigned short* Wb = (unsigned short*)(shift + DDIM);

  k1_stats<<<dim3(4, CHUNKS), 256, 0, stream>>>(x, psum, psq);
  k2_stats_finalize<<<DDIM / 64, 256, 0, stream>>>(psum, psq, gamma, beta, scale, shift);
  k2_wconv<<<(ODIM * DDIM) / 1024, 256, 0, stream>>>(W, Wb);
  k3_bn_gemm<<<NROWS / BM, 512, 0, stream>>>(x, Wb, scale, shift, b, out);
}